// Round 1
// baseline (101.756 us; speedup 1.0000x reference)
//
#include <hip/hip_runtime.h>
#include <math.h>

#define N_OBJ 16
#define P 4096                     // P1 == P2
#define BLOCK 256
#define R 8                        // rows per thread
#define ROWS_PER_BLOCK (BLOCK * R) // 2048
#define ROWBLOCKS (P / ROWS_PER_BLOCK) // 2
#define CQ 16                      // chunks along the min-dimension
#define QCHUNK (P / CQ)            // 256
#define EPSF 1e-12f

// ---------------------------------------------------------------------------
// Kernel 1: init min-buffers to +INF, zero the output scalar, compute masks.
// Blocks [0,128): grid-stride fill of 2*N_OBJ*P ints with 0x7F800000 (+inf).
// Blocks [128,144): block n-128 sums set2[n] (8192 floats) -> mask[n].
// ---------------------------------------------------------------------------
__global__ __launch_bounds__(BLOCK) void k_init(const float* __restrict__ s2,
                                                int* __restrict__ minbuf,
                                                float* __restrict__ maskbuf,
                                                float* __restrict__ out) {
    int bid = blockIdx.x;
    int tid = threadIdx.x;
    if (bid < 128) {
        const int total = 2 * N_OBJ * P; // 131072
        for (int i = bid * BLOCK + tid; i < total; i += 128 * BLOCK)
            minbuf[i] = 0x7F800000; // +inf as float
        if (bid == 0 && tid == 0) out[0] = 0.0f;
    } else {
        int n = bid - 128;
        __shared__ float red[BLOCK];
        float s = 0.0f;
        for (int i = tid; i < 2 * P; i += BLOCK)
            s += s2[n * 2 * P + i];
        red[tid] = s;
        __syncthreads();
        for (int off = BLOCK / 2; off > 0; off >>= 1) {
            if (tid < off) red[tid] += red[tid + off];
            __syncthreads();
        }
        if (tid == 0) maskbuf[n] = (red[0] >= 0.0f) ? 1.0f : 0.0f;
    }
}

// ---------------------------------------------------------------------------
// Kernel 2: pairwise min passes.
// pass 0: rows = set1 points (min over set2)  -> rowmin
// pass 1: rows = set2 points (min over set1)  -> colmin
// Per-pair: s = x2 + y2 - 2(x0*y0 + x1*y1).  Hoist x2 out of the min:
//   track m = min_j fma(-2*x0, y0_j, fma(-2*x1, y1_j, y2_j)); final = m + x2.
// Clamp to EPS (positive) then int-punned atomicMin (valid for floats >= 0).
// ---------------------------------------------------------------------------
__global__ __launch_bounds__(BLOCK) void k_main(const float* __restrict__ s1,
                                                const float* __restrict__ s2,
                                                const float* __restrict__ maskbuf,
                                                int* __restrict__ rowmin,
                                                int* __restrict__ colmin) {
    const int per_pass = N_OBJ * ROWBLOCKS * CQ; // 512
    int bid  = blockIdx.x;
    int pass = bid / per_pass;
    int idx  = bid % per_pass;
    int n    = idx / (ROWBLOCKS * CQ);
    int rem  = idx % (ROWBLOCKS * CQ);
    int rb   = rem / CQ;
    int cq   = rem % CQ;

    if (maskbuf[n] == 0.0f) return; // masked object: contributes 0, skip all work

    const float* T = (pass == 0) ? s1 : s2; // "row" points (one per accumulator)
    const float* S = (pass == 0) ? s2 : s1; // points we minimize over (staged)
    int* outmin    = (pass == 0) ? rowmin : colmin;

    __shared__ float4 lds[QCHUNK];
    int tid = threadIdx.x;

    // Stage S chunk: (y0, y1, y0^2+y1^2)
    {
        int j = tid; // QCHUNK == BLOCK
        int q = cq * QCHUNK + j;
        float2 y = ((const float2*)S)[n * P + q];
        lds[j] = make_float4(y.x, y.y, fmaf(y.x, y.x, y.y * y.y), 0.0f);
    }

    // Load this thread's R rows.
    float a0[R], a1[R], c[R], m[R];
    int rbase = rb * ROWS_PER_BLOCK;
#pragma unroll
    for (int k = 0; k < R; k++) {
        int r = rbase + k * BLOCK + tid;
        float2 x = ((const float2*)T)[n * P + r];
        a0[k] = -2.0f * x.x;
        a1[k] = -2.0f * x.y;
        c[k]  = fmaf(x.x, x.x, x.y * x.y);
        m[k]  = INFINITY;
    }
    __syncthreads();

#pragma unroll 4
    for (int j = 0; j < QCHUNK; j++) {
        float4 v = lds[j]; // broadcast read: all lanes same address, conflict-free
#pragma unroll
        for (int k = 0; k < R; k++) {
            m[k] = fminf(m[k], fmaf(a0[k], v.x, fmaf(a1[k], v.y, v.z)));
        }
    }

#pragma unroll
    for (int k = 0; k < R; k++) {
        int r = rbase + k * BLOCK + tid;
        float val = fmaxf(m[k] + c[k], EPSF); // clip(., EPS): positive => int order ok
        atomicMin(&outmin[n * P + r], __float_as_int(val));
    }
}

// ---------------------------------------------------------------------------
// Kernel 3: per-object finalize. Block n sums sqrt(min) over both directions,
// cost_n = 0.5*(sum1 + sum2)/P ; atomicAdd(out, cost_n/N).
// ---------------------------------------------------------------------------
__global__ __launch_bounds__(BLOCK) void k_obj(const int* __restrict__ rowmin,
                                               const int* __restrict__ colmin,
                                               const float* __restrict__ maskbuf,
                                               float* __restrict__ out) {
    int n = blockIdx.x;
    if (maskbuf[n] == 0.0f) return;
    int tid = threadIdx.x;
    __shared__ float red[BLOCK];
    float s = 0.0f;
    for (int i = tid; i < P; i += BLOCK)
        s += sqrtf(__int_as_float(rowmin[n * P + i]));
    for (int i = tid; i < P; i += BLOCK)
        s += sqrtf(__int_as_float(colmin[n * P + i]));
    red[tid] = s;
    __syncthreads();
    for (int off = BLOCK / 2; off > 0; off >>= 1) {
        if (tid < off) red[tid] += red[tid + off];
        __syncthreads();
    }
    if (tid == 0) {
        float cost = 0.5f * (red[0] / (float)P); // 0.5*(d1+d2), P1==P2
        atomicAdd(out, cost * (1.0f / (float)N_OBJ));
    }
}

extern "C" void kernel_launch(void* const* d_in, const int* in_sizes, int n_in,
                              void* d_out, int out_size, void* d_ws, size_t ws_size,
                              hipStream_t stream) {
    const float* s1 = (const float*)d_in[0]; // [16,4096,2] fp32
    const float* s2 = (const float*)d_in[1]; // [16,4096,2] fp32
    float* out = (float*)d_out;              // scalar fp32

    int*   rowmin  = (int*)d_ws;                       // 65536 ints
    int*   colmin  = rowmin + N_OBJ * P;               // 65536 ints
    float* maskbuf = (float*)(colmin + N_OBJ * P);     // 16 floats

    k_init<<<144, BLOCK, 0, stream>>>(s2, rowmin, maskbuf, out);
    k_main<<<2 * N_OBJ * ROWBLOCKS * CQ, BLOCK, 0, stream>>>(s1, s2, maskbuf,
                                                             rowmin, colmin);
    k_obj<<<N_OBJ, BLOCK, 0, stream>>>(rowmin, colmin, maskbuf, out);
}